// Round 3
// baseline (152.608 us; speedup 1.0000x reference)
//
#include <hip/hip_runtime.h>

// AffineTransform2D, pipelined LDS-staged bilinear sampling.
// im [8,32,256,256,4] f32, thetas [8,6] f32 -> out [8,32,256,256,4] f32.
//
// Block = 16x16 output tile for one b. Per d-plane the tile's source bbox
// (<= 33x33 float4, since thetas in [0,1)) is staged straight into LDS with
// __builtin_amdgcn_global_load_lds (lane-linear dest), double-buffered, with
// a 2-plane-deep pipeline using counted s_waitcnt vmcnt(N) + raw s_barrier
// (T3/T4) instead of __syncthreads' full vmcnt(0) drain.

#define MB_ 8
#define D_  32
#define H_  256
#define W_  256
#define TS  16
#define TR  16
#define CAPD  33                 // max bbox dim (proof: span < 30.12 -> <=33)
#define CAPE  5                  // staging chunks per thread (ceil(33^2/256))
#define SLOTS (CAPE * 256)       // 1280 float4 per buffer

__global__ __launch_bounds__(256) void affine2d_pipe(
    const float* __restrict__ im,
    const float* __restrict__ thetas,
    float* __restrict__ out)
{
    __shared__ float4 tile[2 * SLOTS];   // 40,960 B exactly -> 4 blocks/CU

    const int tid  = threadIdx.x;
    const int bIdx = blockIdx.x;
    const int s0 = (bIdx & 15) * TS;
    const int r0 = ((bIdx >> 4) & 15) * TR;
    const int b  = bIdx >> 8;

    const float t0 = thetas[b*6+0], t1 = thetas[b*6+1], t2 = thetas[b*6+2];
    const float t3 = thetas[b*6+3], t4 = thetas[b*6+4], t5 = thetas[b*6+5];

    const int s = s0 + (tid & 15), r = r0 + (tid >> 4);
    const float x_in = -1.0f + (float)s * (2.0f / 255.0f);
    const float y_in = -1.0f + (float)r * (2.0f / 255.0f);
    const float Xc = (t0*x_in + t1*y_in + t2 + 1.0f) * 0.5f * (float)W_;
    const float Yc = (t3*x_in + t4*y_in + t5 + 1.0f) * 0.5f * (float)H_;

    int x0i = (int)floorf(Xc), y0i = (int)floorf(Yc);
    int x1i = x0i + 1, y1i = y0i + 1;
    x0i = min(max(x0i,0),W_-1);  x1i = min(max(x1i,0),W_-1);
    y0i = min(max(y0i,0),H_-1);  y1i = min(max(y1i,0),H_-1);

    // weights from CLIPPED corners (matches reference)
    const float wa = ((float)x1i - Xc) * ((float)y1i - Yc);
    const float wb = ((float)x1i - Xc) * (Yc - (float)y0i);
    const float wc = (Xc - (float)x0i) * ((float)y1i - Yc);
    const float wd = (Xc - (float)x0i) * (Yc - (float)y0i);

    // ---- block-wide bbox (wave shfl reduce + LDS combine; red[] unioned
    //      into tile[] and consumed before any staging touches LDS) ----
    int xmn=x0i, xmx=x1i, ymn=y0i, ymx=y1i;
#pragma unroll
    for (int off=32; off; off>>=1) {
        xmn=min(xmn,__shfl_xor(xmn,off)); xmx=max(xmx,__shfl_xor(xmx,off));
        ymn=min(ymn,__shfl_xor(ymn,off)); ymx=max(ymx,__shfl_xor(ymx,off));
    }
    int* red = (int*)tile;
    const int wv = tid >> 6;
    if ((tid & 63) == 0) {
        red[wv*4+0]=xmn; red[wv*4+1]=xmx; red[wv*4+2]=ymn; red[wv*4+3]=ymx;
    }
    __syncthreads();
    const int xlo=min(min(red[0],red[4]),  min(red[8], red[12]));
    const int xhi=max(max(red[1],red[5]),  max(red[9], red[13]));
    const int ylo=min(min(red[2],red[6]),  min(red[10],red[14]));
    const int yhi=max(max(red[3],red[7]),  max(red[11],red[15]));
    __syncthreads();   // red consumed by all threads before tile reuse
    const int nx = xhi - xlo + 1;
    const int ny = yhi - ylo + 1;

    const int plane = H_ * W_;
    const float4* __restrict__ imb  = (const float4*)im + b * (D_ * plane);
    float4* __restrict__ outp = (float4*)out + b * (D_ * plane) + r * W_ + s;

    if (nx <= CAPD && ny <= CAPD) {
        // Stage a fixed 1280-slot region: rows ylo.., width nx, rows clamped
        // to H-1 past the bbox (same addresses -> cache hits, no extra HBM).
        // Every wave issues exactly CAPE gll ops/plane -> uniform vmcnt.
        int goff[CAPE];
#pragma unroll
        for (int k = 0; k < CAPE; ++k) {
            const int e  = tid + (k << 8);
            const int yy = e / nx;
            const int xx = e - yy * nx;
            const int row = min(ylo + yy, H_ - 1);
            goff[k] = row * W_ + xlo + xx;
        }
        const int la = (y0i - ylo) * nx + (x0i - xlo);
        const int lb = (y1i - ylo) * nx + (x0i - xlo);
        const int dx = x1i - x0i;
        const int wbase = tid & ~63;          // wave-uniform lane base

        auto stage = [&](int dp, int bi) {
#pragma unroll
            for (int k = 0; k < CAPE; ++k) {
                const float4* src = imb + dp * plane + goff[k];
                float4* dst = &tile[bi * SLOTS + (k << 8) + wbase];
                __builtin_amdgcn_global_load_lds(
                    (const __attribute__((address_space(1))) void*)src,
                    (__attribute__((address_space(3))) void*)dst,
                    16 /*bytes, literal*/, 0, 0);
            }
        };

        stage(0, 0);
        stage(1, 1);

        // vmcnt robustness: steady-state FIFO per wave is
        //   [st(d-2)?, gll(d)x5, st(d-1)?, gll(d+1)x5].
        // vmcnt(5) drains plane d's 5 loads whether or not global stores
        // count toward vmcnt (if they do, it also waits one old store).
        // Last plane: vmcnt(0).
#pragma unroll
        for (int d = 0; d < D_; ++d) {
            if (d == D_ - 1) asm volatile("s_waitcnt vmcnt(0)" ::: "memory");
            else             asm volatile("s_waitcnt vmcnt(5)" ::: "memory");
            asm volatile("s_barrier" ::: "memory");   // rendezvous, no drain

            const float4* tb = &tile[(d & 1) * SLOTS];
            const float4 va = tb[la];
            const float4 vb = tb[lb];
            const float4 vc = tb[la + dx];
            const float4 vd = tb[lb + dx];
            float4 o;
            o.x = va.x*wa + vb.x*wb + vc.x*wc + vd.x*wd;
            o.y = va.y*wa + vb.y*wb + vc.y*wc + vd.y*wd;
            o.z = va.z*wa + vb.z*wb + vc.z*wc + vd.z*wd;
            o.w = va.w*wa + vb.w*wb + vc.w*wc + vd.w*wd;
            outp[d * plane] = o;

            asm volatile("s_barrier" ::: "memory");   // all reads of buf done
            if (d + 2 < D_) stage(d + 2, d & 1);      // overwrite freed buffer
        }
    } else {
        // fallback: direct global gathers (block-uniform branch, no barriers)
        const int ia = y0i*W_ + x0i, ib2 = y1i*W_ + x0i;
        const int ic = y0i*W_ + x1i, id2 = y1i*W_ + x1i;
        for (int d = 0; d < D_; ++d) {
            const float4* pl = imb + d * plane;
            const float4 va = pl[ia], vb = pl[ib2], vc = pl[ic], vd = pl[id2];
            float4 o;
            o.x = va.x*wa + vb.x*wb + vc.x*wc + vd.x*wd;
            o.y = va.y*wa + vb.y*wb + vc.y*wc + vd.y*wd;
            o.z = va.z*wa + vb.z*wb + vc.z*wc + vd.z*wd;
            o.w = va.w*wa + vb.w*wb + vc.w*wc + vd.w*wd;
            outp[d * plane] = o;
        }
    }
}

extern "C" void kernel_launch(void* const* d_in, const int* in_sizes, int n_in,
                              void* d_out, int out_size, void* d_ws, size_t ws_size,
                              hipStream_t stream) {
    const float* im     = (const float*)d_in[0];
    const float* thetas = (const float*)d_in[1];
    float* out          = (float*)d_out;

    dim3 grid(MB_ * (H_ / TR) * (W_ / TS));   // 2048
    dim3 block(TS * TR);                      // 256
    affine2d_pipe<<<grid, block, 0, stream>>>(im, thetas, out);
}

// Round 4
// 95.038 us; speedup vs baseline: 1.6058x; 1.6058x over previous
//
#include <hip/hip_runtime.h>

// AffineTransform2D, depth-2 register-prefetch + single-buffer LDS staging.
// im [8,32,256,256,4] f32, thetas [8,6] f32 -> out [8,32,256,256,4] f32.
//
// Block = 16x16 output tile of one b. Per d-plane, the tile's source bbox
// (<= 33x33 float4 since thetas in [0,1)) is staged into ONE 17.4 KB LDS
// buffer (8 blocks/CU). The "second buffer" is registers: pA/pB each hold a
// full plane's staging chunks, loaded 2 planes ahead, so the vmcnt wait the
// compiler inserts before ds_write has ~2 iterations of slack. Loop is
// unrolled x2 with statically-named pA/pB (no runtime-indexed arrays).

#define MB_ 8
#define D_  32
#define H_  256
#define W_  256
#define TS  16
#define TR  16
#define CAPD 33                  // max bbox dim (span < 15.06*2 + 2 -> <=33)
#define CAPE 5                   // ceil(33*33 / 256)

__global__ __launch_bounds__(256) void affine2d_p2(
    const float* __restrict__ im,
    const float* __restrict__ thetas,
    float* __restrict__ out)
{
    __shared__ float4 tile[CAPD * CAPD];   // 17,424 B

    const int tid  = threadIdx.x;
    const int bIdx = blockIdx.x;
    const int s0 = (bIdx & 15) * TS;
    const int r0 = ((bIdx >> 4) & 15) * TR;
    const int b  = bIdx >> 8;

    const float t0 = thetas[b*6+0], t1 = thetas[b*6+1], t2 = thetas[b*6+2];
    const float t3 = thetas[b*6+3], t4 = thetas[b*6+4], t5 = thetas[b*6+5];

    const int s = s0 + (tid & 15), r = r0 + (tid >> 4);
    const float x_in = -1.0f + (float)s * (2.0f / 255.0f);
    const float y_in = -1.0f + (float)r * (2.0f / 255.0f);
    const float Xc = (t0*x_in + t1*y_in + t2 + 1.0f) * 0.5f * (float)W_;
    const float Yc = (t3*x_in + t4*y_in + t5 + 1.0f) * 0.5f * (float)H_;

    int x0i = (int)floorf(Xc), y0i = (int)floorf(Yc);
    int x1i = x0i + 1, y1i = y0i + 1;
    x0i = min(max(x0i,0),W_-1);  x1i = min(max(x1i,0),W_-1);
    y0i = min(max(y0i,0),H_-1);  y1i = min(max(y1i,0),H_-1);

    const float wa = ((float)x1i - Xc) * ((float)y1i - Yc);
    const float wb = ((float)x1i - Xc) * (Yc - (float)y0i);
    const float wc = (Xc - (float)x0i) * ((float)y1i - Yc);
    const float wd = (Xc - (float)x0i) * (Yc - (float)y0i);

    // ---- block bbox: wave shfl-reduce, combine via LDS (aliased on tile) --
    int xmn=x0i, xmx=x1i, ymn=y0i, ymx=y1i;
#pragma unroll
    for (int off=32; off; off>>=1) {
        xmn=min(xmn,__shfl_xor(xmn,off)); xmx=max(xmx,__shfl_xor(xmx,off));
        ymn=min(ymn,__shfl_xor(ymn,off)); ymx=max(ymx,__shfl_xor(ymx,off));
    }
    int* red = (int*)tile;
    if ((tid & 63) == 0) {
        const int wv = tid >> 6;
        red[wv*4+0]=xmn; red[wv*4+1]=xmx; red[wv*4+2]=ymn; red[wv*4+3]=ymx;
    }
    __syncthreads();
    const int xlo=min(min(red[0],red[4]),  min(red[8], red[12]));
    const int xhi=max(max(red[1],red[5]),  max(red[9], red[13]));
    const int ylo=min(min(red[2],red[6]),  min(red[10],red[14]));
    const int yhi=max(max(red[3],red[7]),  max(red[11],red[15]));
    __syncthreads();                       // red consumed before tile reuse
    const int nx = xhi - xlo + 1;
    const int ny = yhi - ylo + 1;

    const int plane = H_ * W_;
    const float4* __restrict__ imb  = (const float4*)im + b * (D_ * plane);
    float4* __restrict__ outp = (float4*)out + b * (D_ * plane) + r * W_ + s;

    if (nx <= CAPD && ny <= CAPD) {
        const int total = nx * ny;              // block-uniform
        // per-thread staging slots (exact; guarded by ok[k])
        int  goff[CAPE];
        bool ok[CAPE];
#pragma unroll
        for (int k = 0; k < CAPE; ++k) {
            const int e  = tid + (k << 8);
            ok[k] = (e < total);
            const int ec = ok[k] ? e : 0;
            const int yy = ec / nx;
            const int xx = ec - yy * nx;
            goff[k] = (ylo + yy) * W_ + xlo + xx;
        }
        const int la = (y0i - ylo) * nx + (x0i - xlo);
        const int lb = (y1i - ylo) * nx + (x0i - xlo);
        const int dx = x1i - x0i;

        float4 pA0,pA1,pA2,pA3,pA4, pB0,pB1,pB2,pB3,pB4;

#define LOADP(P, dp)                                                     \
        do { const float4* pl = imb + (dp) * plane;                      \
             if (ok[0]) P##0 = pl[goff[0]];                              \
             if (ok[1]) P##1 = pl[goff[1]];                              \
             if (ok[2]) P##2 = pl[goff[2]];                              \
             if (ok[3]) P##3 = pl[goff[3]];                              \
             if (ok[4]) P##4 = pl[goff[4]]; } while (0)

#define WRITEP(P)                                                        \
        do { if (ok[0]) tile[tid        ] = P##0;                        \
             if (ok[1]) tile[tid +  256 ] = P##1;                        \
             if (ok[2]) tile[tid +  512 ] = P##2;                        \
             if (ok[3]) tile[tid +  768 ] = P##3;                        \
             if (ok[4]) tile[tid + 1024 ] = P##4; } while (0)

#define COMPUTE(dp)                                                      \
        do { const float4 va = tile[la];                                 \
             const float4 vb = tile[lb];                                 \
             const float4 vc = tile[la + dx];                            \
             const float4 vd = tile[lb + dx];                            \
             float4 o;                                                   \
             o.x = va.x*wa + vb.x*wb + vc.x*wc + vd.x*wd;                \
             o.y = va.y*wa + vb.y*wb + vc.y*wc + vd.y*wd;                \
             o.z = va.z*wa + vb.z*wb + vc.z*wc + vd.z*wd;                \
             o.w = va.w*wa + vb.w*wb + vc.w*wc + vd.w*wd;                \
             outp[(dp) * plane] = o; } while (0)

        LOADP(pA, 0);
        LOADP(pB, 1);

#pragma unroll 1
        for (int dd = 0; dd < D_ / 2; ++dd) {
            const int d = dd * 2;
            // ---- plane d (from pA) ----
            __syncthreads();              // readers of previous plane done
            WRITEP(pA);                   // compiler waits pA's loads here
            if (dd < D_/2 - 1) LOADP(pA, d + 2);
            __syncthreads();              // tile ready
            COMPUTE(d);
            // ---- plane d+1 (from pB) ----
            __syncthreads();
            WRITEP(pB);
            if (dd < D_/2 - 1) LOADP(pB, d + 3);
            __syncthreads();
            COMPUTE(d + 1);
        }
#undef LOADP
#undef WRITEP
#undef COMPUTE
    } else {
        // fallback: direct global gathers (block-uniform branch)
        const int ia = y0i*W_ + x0i, ib2 = y1i*W_ + x0i;
        const int ic = y0i*W_ + x1i, id2 = y1i*W_ + x1i;
        for (int d = 0; d < D_; ++d) {
            const float4* pl = imb + d * plane;
            const float4 va = pl[ia], vb = pl[ib2], vc = pl[ic], vd = pl[id2];
            float4 o;
            o.x = va.x*wa + vb.x*wb + vc.x*wc + vd.x*wd;
            o.y = va.y*wa + vb.y*wb + vc.y*wc + vd.y*wd;
            o.z = va.z*wa + vb.z*wb + vc.z*wc + vd.z*wd;
            o.w = va.w*wa + vb.w*wb + vc.w*wc + vd.w*wd;
            outp[d * plane] = o;
        }
    }
}

extern "C" void kernel_launch(void* const* d_in, const int* in_sizes, int n_in,
                              void* d_out, int out_size, void* d_ws, size_t ws_size,
                              hipStream_t stream) {
    const float* im     = (const float*)d_in[0];
    const float* thetas = (const float*)d_in[1];
    float* out          = (float*)d_out;

    dim3 grid(MB_ * (H_ / TR) * (W_ / TS));   // 2048
    dim3 block(TS * TR);                      // 256
    affine2d_p2<<<grid, block, 0, stream>>>(im, thetas, out);
}

// Round 6
// 66.978 us; speedup vs baseline: 2.2785x; 1.4189x over previous
//
#include <hip/hip_runtime.h>

// AffineTransform2D: reg-prefetch depth-2 + double LDS buffer + raw s_barrier.
// im [8,32,256,256,4] f32, thetas [8,6] f32 -> out [8,32,256,256,4] f32.
//
// Block = 16x16 output tile of one b. Per d-plane the tile's source bbox
// (<= 33x33 float4, thetas in [0,1)) is staged via registers into one of two
// LDS buffers. In-loop barriers are `s_waitcnt lgkmcnt(0); s_barrier` ONLY —
// no vmcnt(0) drain — so the plane d+2 prefetch loads issued at iter d keep
// their full 2-iteration slack (the compiler emits exact counted vmcnt waits
// for the register dependencies at each WRITEP). One barrier per plane:
// RAW covered by lgkm0+barrier; WAR on a buffer is fenced by the *next*
// plane's barrier (reads drain via FMA data-deps before any wave reaches it).

#define MB_ 8
#define D_  32
#define H_  256
#define W_  256
#define TS  16
#define TR  16
#define CAPD 33                  // max bbox dim: span < 15.06*2 + 2 -> <= 33
#define CAPE 5                   // ceil(33*33 / 256) staging chunks/thread

typedef float nfloat4 __attribute__((ext_vector_type(4)));  // native vec for nt-store

__global__ __launch_bounds__(256) void affine2d_db(
    const float* __restrict__ im,
    const float* __restrict__ thetas,
    float* __restrict__ out)
{
    __shared__ float4 tile0[CAPD * CAPD];   // 17,424 B
    __shared__ float4 tile1[CAPD * CAPD];   // 17,424 B  (total 34,848 -> 4 blk/CU)

    const int tid  = threadIdx.x;
    const int bIdx = blockIdx.x;
    const int s0 = (bIdx & 15) * TS;
    const int r0 = ((bIdx >> 4) & 15) * TR;
    const int b  = bIdx >> 8;

    const float t0 = thetas[b*6+0], t1 = thetas[b*6+1], t2 = thetas[b*6+2];
    const float t3 = thetas[b*6+3], t4 = thetas[b*6+4], t5 = thetas[b*6+5];

    const int s = s0 + (tid & 15), r = r0 + (tid >> 4);
    const float x_in = -1.0f + (float)s * (2.0f / 255.0f);
    const float y_in = -1.0f + (float)r * (2.0f / 255.0f);
    const float Xc = (t0*x_in + t1*y_in + t2 + 1.0f) * 0.5f * (float)W_;
    const float Yc = (t3*x_in + t4*y_in + t5 + 1.0f) * 0.5f * (float)H_;

    int x0i = (int)floorf(Xc), y0i = (int)floorf(Yc);
    int x1i = x0i + 1, y1i = y0i + 1;
    x0i = min(max(x0i,0),W_-1);  x1i = min(max(x1i,0),W_-1);
    y0i = min(max(y0i,0),H_-1);  y1i = min(max(y1i,0),H_-1);

    const float wa = ((float)x1i - Xc) * ((float)y1i - Yc);
    const float wb = ((float)x1i - Xc) * (Yc - (float)y0i);
    const float wc = (Xc - (float)x0i) * ((float)y1i - Yc);
    const float wd = (Xc - (float)x0i) * (Yc - (float)y0i);

    // ---- block bbox: wave shfl-reduce, combine via LDS (aliased on tile0) --
    int xmn=x0i, xmx=x1i, ymn=y0i, ymx=y1i;
#pragma unroll
    for (int off=32; off; off>>=1) {
        xmn=min(xmn,__shfl_xor(xmn,off)); xmx=max(xmx,__shfl_xor(xmx,off));
        ymn=min(ymn,__shfl_xor(ymn,off)); ymx=max(ymx,__shfl_xor(ymx,off));
    }
    int* red = (int*)tile0;
    if ((tid & 63) == 0) {
        const int wv = tid >> 6;
        red[wv*4+0]=xmn; red[wv*4+1]=xmx; red[wv*4+2]=ymn; red[wv*4+3]=ymx;
    }
    __syncthreads();
    const int xlo=min(min(red[0],red[4]),  min(red[8], red[12]));
    const int xhi=max(max(red[1],red[5]),  max(red[9], red[13]));
    const int ylo=min(min(red[2],red[6]),  min(red[10],red[14]));
    const int yhi=max(max(red[3],red[7]),  max(red[11],red[15]));
    __syncthreads();                       // red consumed before tile0 reuse
    const int nx = xhi - xlo + 1;
    const int ny = yhi - ylo + 1;

    const int plane = H_ * W_;
    const float4* __restrict__ imb  = (const float4*)im + b * (D_ * plane);
    float4* __restrict__ outp = (float4*)out + b * (D_ * plane) + r * W_ + s;

    if (nx <= CAPD && ny <= CAPD) {
        const int total = nx * ny;              // block-uniform
        int  goff[CAPE];
        bool ok[CAPE];
#pragma unroll
        for (int k = 0; k < CAPE; ++k) {
            const int e  = tid + (k << 8);
            ok[k] = (e < total);
            const int ec = ok[k] ? e : 0;
            const int yy = ec / nx;
            const int xx = ec - yy * nx;
            goff[k] = (ylo + yy) * W_ + xlo + xx;
        }
        const int la = (y0i - ylo) * nx + (x0i - xlo);
        const int lb = (y1i - ylo) * nx + (x0i - xlo);
        const int dx = x1i - x0i;

        float4 pA0,pA1,pA2,pA3,pA4, pB0,pB1,pB2,pB3,pB4;

#define LOADP(P, dp)                                                     \
        do { const float4* pl = imb + (dp) * plane;                      \
             if (ok[0]) P##0 = pl[goff[0]];                              \
             if (ok[1]) P##1 = pl[goff[1]];                              \
             if (ok[2]) P##2 = pl[goff[2]];                              \
             if (ok[3]) P##3 = pl[goff[3]];                              \
             if (ok[4]) P##4 = pl[goff[4]]; } while (0)

#define WRITEP(P, TB)                                                    \
        do { if (ok[0]) TB[tid       ] = P##0;                           \
             if (ok[1]) TB[tid +  256] = P##1;                           \
             if (ok[2]) TB[tid +  512] = P##2;                           \
             if (ok[3]) TB[tid +  768] = P##3;                           \
             if (ok[4]) TB[tid + 1024] = P##4; } while (0)

// lgkmcnt(0): own ds_writes done; s_barrier: everyone's done. NO vmcnt drain.
#define LBAR() asm volatile("s_waitcnt lgkmcnt(0)\n\ts_barrier" ::: "memory")

#define COMPUTE(dp, TB)                                                  \
        do { const float4 va = TB[la];                                   \
             const float4 vb = TB[lb];                                   \
             const float4 vc = TB[la + dx];                              \
             const float4 vd = TB[lb + dx];                              \
             nfloat4 o;                                                  \
             o.x = va.x*wa + vb.x*wb + vc.x*wc + vd.x*wd;                \
             o.y = va.y*wa + vb.y*wb + vc.y*wc + vd.y*wd;                \
             o.z = va.z*wa + vb.z*wb + vc.z*wc + vd.z*wd;                \
             o.w = va.w*wa + vb.w*wb + vc.w*wc + vd.w*wd;                \
             __builtin_nontemporal_store(o, (nfloat4*)&outp[(dp) * plane]); \
        } while (0)

        LOADP(pA, 0);
        LOADP(pB, 1);

#pragma unroll 1
        for (int dd = 0; dd < D_ / 2; ++dd) {
            const int d = dd * 2;
            // ---- plane d (pA -> tile0) ----
            WRITEP(pA, tile0);                 // counted vmcnt wait (pA only)
            if (dd < D_/2 - 1) LOADP(pA, d + 2);
            LBAR();
            COMPUTE(d, tile0);
            // ---- plane d+1 (pB -> tile1) ----
            WRITEP(pB, tile1);
            if (dd < D_/2 - 1) LOADP(pB, d + 3);
            LBAR();
            COMPUTE(d + 1, tile1);
        }
#undef LOADP
#undef WRITEP
#undef COMPUTE
#undef LBAR
    } else {
        // fallback: direct global gathers (block-uniform branch, no barriers)
        const int ia = y0i*W_ + x0i, ib2 = y1i*W_ + x0i;
        const int ic = y0i*W_ + x1i, id2 = y1i*W_ + x1i;
        for (int d = 0; d < D_; ++d) {
            const float4* pl = imb + d * plane;
            const float4 va = pl[ia], vb = pl[ib2], vc = pl[ic], vd = pl[id2];
            float4 o;
            o.x = va.x*wa + vb.x*wb + vc.x*wc + vd.x*wd;
            o.y = va.y*wa + vb.y*wb + vc.y*wc + vd.y*wd;
            o.z = va.z*wa + vb.z*wb + vc.z*wc + vd.z*wd;
            o.w = va.w*wa + vb.w*wb + vc.w*wc + vd.w*wd;
            outp[d * plane] = o;
        }
    }
}

extern "C" void kernel_launch(void* const* d_in, const int* in_sizes, int n_in,
                              void* d_out, int out_size, void* d_ws, size_t ws_size,
                              hipStream_t stream) {
    const float* im     = (const float*)d_in[0];
    const float* thetas = (const float*)d_in[1];
    float* out          = (float*)d_out;

    dim3 grid(MB_ * (H_ / TR) * (W_ / TS));   // 2048
    dim3 block(TS * TR);                      // 256
    affine2d_db<<<grid, block, 0, stream>>>(im, thetas, out);
}